// Round 16
// baseline (219.733 us; speedup 1.0000x reference)
//
#include <hip/hip_runtime.h>
#include <stdint.h>

// Problem: B=8, Lq=Lv=2048, Din=Dout=512, all f32 in/out.
// out[b][l][0:512)=o, [512:1024)=q, [1024:1536)=mv broadcast.
// v15b = v15 with the workspace allocation bug fixed: biasb no longer
// overlaps part (part is 1MB; biasb was placed 128KB into it -> exp(garbage)
// -> NaN). Kernel code byte-identical to v15.
// v15: 512 blocks x 32 q-rows, 2 blocks/CU (73.5KB LDS, 128-VGPR cap).
// Single-buffered A/T tiles (A one tile ahead of T); per-iter vmcnt(0) drain
// hidden by the sibling block. Roles: 2S + 4PV + 2C. Mask as bf16 bias.

typedef __attribute__((ext_vector_type(8))) short short8v;
typedef __attribute__((ext_vector_type(4))) float f32x4;

#define LQ 2048
#define LV 2048
#define DIN 512
#define DOUT 512
#define NB 8
#define KT 32   // KV tile

__device__ __forceinline__ unsigned short f2bf(float x){
    union { float f; unsigned u; } v; v.f = x;
    unsigned r = v.u + 0x7fffu + ((v.u >> 16) & 1u);
    return (unsigned short)(r >> 16);
}
__device__ __forceinline__ float bf2f(unsigned short h){
    union { unsigned u; float f; } v; v.u = ((unsigned)h) << 16; return v.f;
}

__device__ __forceinline__ void gload16(const void* g, void* l){
    __builtin_amdgcn_global_load_lds((const __attribute__((address_space(1))) void*)g,
                                     (__attribute__((address_space(3))) void*)l, 16, 0, 0);
}

#define SBAR   do{ __builtin_amdgcn_s_barrier(); __builtin_amdgcn_sched_barrier(0); }while(0)
#define LGKM0  do{ asm volatile("s_waitcnt lgkmcnt(0)" ::: "memory"); \
                   __builtin_amdgcn_sched_barrier(0); }while(0)
#define VMCNT0 do{ asm volatile("s_waitcnt vmcnt(0)" ::: "memory"); \
                   __builtin_amdgcn_sched_barrier(0); }while(0)

#define MFMA16(a, bfr, c) __builtin_amdgcn_mfma_f32_16x16x32_bf16(a, bfr, c, 0, 0, 0)

// kernel [DIN][DOUT] f32 -> kT [DOUT][DIN] bf16, scaled by 0.1 (folds the /10)
__global__ void prep_kT(const float* __restrict__ k, unsigned short* __restrict__ kT){
    __shared__ float tile[32][33];
    int tx = threadIdx.x & 31, ty = threadIdx.x >> 5;
    int kb = blockIdx.x, eb = blockIdx.y;
    #pragma unroll
    for (int p = 0; p < 4; ++p){
        int r = ty + p*8;
        tile[r][tx] = k[(size_t)(kb*32 + r)*DOUT + eb*32 + tx];
    }
    __syncthreads();
    #pragma unroll
    for (int p = 0; p < 4; ++p){
        int r = ty + p*8;
        kT[(size_t)(eb*32 + r)*DIN + kb*32 + tx] = f2bf(tile[tx][r] * 0.1f);
    }
}

// v f32 -> v bf16 [b][j][e] and vT bf16 [b][e][j] + masked-max partials
// + bf16 additive-bias row biasb[b][j] = bf16((mask-1)*1e10)
__global__ void prep_v(const float* __restrict__ v, const float* __restrict__ mask,
                       unsigned short* __restrict__ vbf, unsigned short* __restrict__ vT,
                       float* __restrict__ part, unsigned short* __restrict__ biasb){
    __shared__ float tile[32][33];
    __shared__ float pmax_l[8][33];
    int tx = threadIdx.x & 31, ty = threadIdx.x >> 5;
    int jb = blockIdx.x, eb = blockIdx.y, b = blockIdx.z;
    const size_t vbase = (size_t)b*LV*DOUT;
    #pragma unroll
    for (int p = 0; p < 4; ++p){
        int r = ty + p*8;
        size_t idx = vbase + (size_t)(jb*32 + r)*DOUT + eb*32 + tx;
        float val = v[idx];
        tile[r][tx] = val;
        vbf[idx] = f2bf(val);
    }
    __syncthreads();
    const size_t tbase = (size_t)b*DOUT*LV;
    #pragma unroll
    for (int p = 0; p < 4; ++p){
        int r = ty + p*8;
        vT[tbase + (size_t)(eb*32 + r)*LV + jb*32 + tx] = f2bf(tile[tx][r]);
    }
    if (eb == 0 && threadIdx.x < 32){
        float msk = mask[b*LV + jb*32 + threadIdx.x];
        biasb[b*2048 + jb*32 + threadIdx.x] = f2bf((msk - 1.0f)*1e10f);
    }
    float m = -3e38f;
    #pragma unroll
    for (int k2 = 0; k2 < 4; ++k2){
        int j = ty*4 + k2;
        float msk = mask[b*LV + jb*32 + j];
        m = fmaxf(m, tile[j][tx] - (1.0f - msk)*1e10f);
    }
    pmax_l[ty][tx] = m;
    __syncthreads();
    if (ty == 0){
        float mm = pmax_l[0][tx];
        #pragma unroll
        for (int c = 1; c < 8; ++c) mm = fmaxf(mm, pmax_l[c][tx]);
        part[((size_t)b*64 + jb)*DOUT + eb*32 + tx] = mm;
    }
}

__global__ void mv_final(const float* __restrict__ part, float* __restrict__ mv){
    int b = blockIdx.x; int e = threadIdx.x;
    float m = -3e38f;
    #pragma unroll
    for (int c = 0; c < 64; ++c) m = fmaxf(m, part[((size_t)b*64 + c)*DOUT + e]);
    mv[b*DOUT + e] = m;
}

__global__ __launch_bounds__(512, 4) void flash(const unsigned short* __restrict__ kT,
                                                const unsigned short* __restrict__ vbf,
                                                const unsigned short* __restrict__ vT,
                                                const unsigned short* __restrict__ biasb,
                                                const float* __restrict__ qf32,
                                                const float* __restrict__ mv,
                                                float* __restrict__ out){
    __shared__ __align__(16) short A_t[KT*512];        // 32KB: v tile [j][e] unit^(j&7); prologue qwL
    __shared__ __align__(16) short T_t[512*KT];        // 32KB: vT tile [e][j] slot^((e>>1)&3); prologue 2x16KB kT chunks
    __shared__ __align__(16) unsigned short maskB[2048]; // 4KB bf16 bias row
    __shared__ short P_lds[2][2][16][40];              // parity x i-block x row x j
    __shared__ float sB[32];

    const int bid = blockIdx.x;
    const int b = bid & 7, qt = bid >> 3;   // batch -> XCD pin; qt 0..63
    const int tid = threadIdx.x;
    const int w = tid >> 6, lane = tid & 63;
    const int li = lane & 15, lg = lane >> 4;
    const int i0 = qt*32;

    const unsigned short* vb  = vbf + (size_t)b*LV*DOUT;
    const unsigned short* vTb = vT  + (size_t)b*DOUT*LV;

    // staging: wave w covers A rows w*4..+3, T chunks w*4..+3, kT-chunk rows w*2..+1
    auto stageA = [&](int j0g){
        #pragma unroll
        for (int p = 0; p < 4; ++p){
            int j = w*4 + p;
            gload16(vb + (size_t)(j0g + j)*DOUT + ((lane ^ (j&7))*8), &A_t[j*512]);
        }
    };
    auto stageT = [&](int j0g){
        #pragma unroll
        for (int p = 0; p < 4; ++p){
            int c = w*4 + p;
            int e = c*16 + (lane >> 2);
            gload16(vTb + (size_t)e*LV + j0g + (((lane&3) ^ ((lane>>3)&3))*8), &T_t[c*512]);
        }
    };
    auto stageK = [&](int ch, int buf){   // 16 kT e-rows per chunk
        #pragma unroll
        for (int n = 0; n < 2; ++n){
            int er = w*2 + n;
            gload16(kT + (size_t)(ch*16 + er)*DIN + ((lane ^ (er&7))*8),
                    (char*)&T_t[0] + buf*16384 + er*1024);
        }
    };

    const bool isS = (w < 2);
    const int key = li & 7;

    // ======= prologue: fused qw GEMM (S-wave w: rows i0 + w*16 + li) =======
    short8v qf[16];
    {
        short8v qb[16];
        if (isS){
            const float* qp = qf32 + (size_t)(b*LQ + i0 + w*16 + li)*DIN;
            #pragma unroll
            for (int ks = 0; ks < 16; ++ks){
                float4 lo = *(const float4*)(qp + ks*32 + lg*8);
                float4 hi = *(const float4*)(qp + ks*32 + lg*8 + 4);
                short8v t;
                t[0]=(short)f2bf(lo.x); t[1]=(short)f2bf(lo.y); t[2]=(short)f2bf(lo.z); t[3]=(short)f2bf(lo.w);
                t[4]=(short)f2bf(hi.x); t[5]=(short)f2bf(hi.y); t[6]=(short)f2bf(hi.z); t[7]=(short)f2bf(hi.w);
                qb[ks] = t;
            }
        }
        char* qwL = (char*)&A_t[0] + w*16384;   // [16 rows][512 e] bf16, swizzled

        stageK(0, 0); VMCNT0; SBAR;
        for (int ch = 0; ch < 32; ++ch){
            if (ch + 1 < 32) stageK(ch + 1, (ch + 1) & 1);
            if (isS){
                const short* Kc = &T_t[(ch & 1)*8192];   // 16 rows x 512 shorts
                f32x4 a0 = (f32x4){0.f,0.f,0.f,0.f}, a1 = a0;
                #pragma unroll
                for (int ks = 0; ks < 16; ks += 2){
                    short8v f0 = *(const short8v*)&Kc[li*512 + (((ks*4 + lg) ^ key)*8)];
                    a0 = MFMA16(f0, qb[ks], a0);
                    short8v f1 = *(const short8v*)&Kc[li*512 + ((((ks+1)*4 + lg) ^ key)*8)];
                    a1 = MFMA16(f1, qb[ks+1], a1);
                }
                unsigned p0 = (unsigned)f2bf(a0[0] + a1[0]) | ((unsigned)f2bf(a0[1] + a1[1]) << 16);
                unsigned p1 = (unsigned)f2bf(a0[2] + a1[2]) | ((unsigned)f2bf(a0[3] + a1[3]) << 16);
                unsigned long long pk = (unsigned long long)p0 | ((unsigned long long)p1 << 32);
                *(unsigned long long*)(qwL + li*1024 + (((4*ch + lg) ^ (key << 1))*8)) = pk;
            }
            VMCNT0; SBAR;          // next chunk landed (all waves)
        }
        if (isS){
            LGKM0;                 // qwL writes landed (same-wave ds ordering safety)
            #pragma unroll
            for (int ks = 0; ks < 16; ++ks)
                qf[ks] = *(const short8v*)(qwL + li*1024 + (((ks*4 + lg) ^ key)*16));
        }
        LGKM0; SBAR;               // qf reads retired; A_t/T_t free
    }

    // ======= main prologue: A(0)+bias -> computeS(0) -> A(1)+T(0) =======
    stageA(0);
    if (w < 4) gload16((const char*)biasb + b*4096 + w*1024 + lane*16,
                       (char*)&maskB[0] + w*1024);
    VMCNT0; SBAR;

    float srun = 0.0f;

    auto computeS = [&](int jn){
        const int pn = jn & 1;
        const int j0 = jn*KT;
        unsigned long long B0 = *(const unsigned long long*)&maskB[j0 + 4*lg];
        unsigned long long B1 = *(const unsigned long long*)&maskB[j0 + 16 + 4*lg];

        f32x4 s0a = (f32x4){0.f,0.f,0.f,0.f}, s0b = s0a, s1a = s0a, s1b = s0a;
        __builtin_amdgcn_s_setprio(1);
        #pragma unroll
        for (int ks = 0; ks < 8; ++ks){
            short8v a = *(const short8v*)&A_t[li*512 + (((ks*4 + lg)^key)*8)];
            s0a = MFMA16(a, qf[ks], s0a);
        }
        #pragma unroll
        for (int ks = 8; ks < 16; ++ks){
            short8v a = *(const short8v*)&A_t[li*512 + (((ks*4 + lg)^key)*8)];
            s0b = MFMA16(a, qf[ks], s0b);
        }
        #pragma unroll
        for (int ks = 0; ks < 8; ++ks){
            short8v a = *(const short8v*)&A_t[(li+16)*512 + (((ks*4 + lg)^key)*8)];
            s1a = MFMA16(a, qf[ks], s1a);
        }
        #pragma unroll
        for (int ks = 8; ks < 16; ++ks){
            short8v a = *(const short8v*)&A_t[(li+16)*512 + (((ks*4 + lg)^key)*8)];
            s1b = MFMA16(a, qf[ks], s1b);
        }
        __builtin_amdgcn_s_setprio(0);

        // max-free softmax: P = exp(S + bias) (|S| <= ~15; f32-safe)
        float p[8]; float psum = 0.f;
        #pragma unroll
        for (int r = 0; r < 4; ++r){
            float b0 = bf2f((unsigned short)((B0 >> (16*r)) & 0xFFFFull));
            float b1 = bf2f((unsigned short)((B1 >> (16*r)) & 0xFFFFull));
            p[r]     = __expf(s0a[r] + s0b[r] + b0);
            p[4 + r] = __expf(s1a[r] + s1b[r] + b1);
        }
        #pragma unroll
        for (int k = 0; k < 8; ++k) psum += p[k];
        srun += psum;

        #pragma unroll
        for (int s2 = 0; s2 < 2; ++s2)
            #pragma unroll
            for (int k = 0; k < 2; ++k){
                unsigned lo2 = f2bf(p[s2*4 + 2*k]);
                unsigned hi2 = f2bf(p[s2*4 + 2*k + 1]);
                *(unsigned*)&P_lds[pn][w][li][s2*16 + 4*lg + 2*k] = lo2 | (hi2 << 16);
            }
    };

    if (isS) computeS(0);
    LGKM0; SBAR;                   // P(0) published; A(0) reads done
    stageA(KT); stageT(0);         // A := tile 1, T := tile 0
    VMCNT0; SBAR;

    // ======= main loop: A holds jt+1, T holds jt, P(jt) ready =======
    if (isS){
        for (int jt = 0; jt < 64; ++jt){
            if (jt < 63) computeS(jt + 1);
            else {
                srun += __shfl_xor(srun, 16);
                srun += __shfl_xor(srun, 32);
                if (lg == 0) sB[w*16 + li] = srun;
            }
            LGKM0; SBAR;                        // B1
            if (jt <= 61) stageA((jt+2)*KT);
            if (jt <= 62) stageT((jt+1)*KT);
            VMCNT0; SBAR;                       // B2
        }
    } else if (w < 6){
        const int wp = w - 2;
        const int keyT = (li >> 1) & 3;
        f32x4 acc[2][8];
        #pragma unroll
        for (int mt = 0; mt < 2; ++mt)
            #pragma unroll
            for (int nt = 0; nt < 8; ++nt) acc[mt][nt] = (f32x4){0.f,0.f,0.f,0.f};

        for (int jt = 0; jt < 64; ++jt){
            const int pc = jt & 1;
            short8v pa[2];
            #pragma unroll
            for (int mt = 0; mt < 2; ++mt)
                pa[mt] = *(const short8v*)&P_lds[pc][mt][li][lg*8];
            __builtin_amdgcn_s_setprio(1);
            #pragma unroll
            for (int nt = 0; nt < 8; ++nt){
                int e_local = (wp*8 + nt)*16 + li;
                short8v vf = *(const short8v*)&T_t[e_local*KT + ((lg ^ keyT)*8)];
                #pragma unroll
                for (int mt = 0; mt < 2; ++mt)
                    acc[mt][nt] = MFMA16(pa[mt], vf, acc[mt][nt]);
            }
            __builtin_amdgcn_s_setprio(0);

            SBAR;                               // B1
            if (jt <= 61) stageA((jt+2)*KT);
            if (jt <= 62) stageT((jt+1)*KT);
            VMCNT0; SBAR;                       // B2
        }

        // epilogue: normalize + write o (sB published during jt=63 compute)
        #pragma unroll
        for (int mt = 0; mt < 2; ++mt){
            f32x4 s4 = *(const f32x4*)&sB[mt*16 + 4*lg];
            f32x4 inv;
            #pragma unroll
            for (int r = 0; r < 4; ++r) inv[r] = 1.0f / s4[r];
            #pragma unroll
            for (int nt = 0; nt < 8; ++nt)
                #pragma unroll
                for (int r = 0; r < 4; ++r)
                    out[(size_t)(b*LQ + i0 + mt*16 + 4*lg + r)*1536 + wp*128 + nt*16 + li]
                        = acc[mt][nt][r]*inv[r];
        }
    } else {
        // C role: staging + in-loop q/mv copy (one row-section per jt)
        const float4* q4  = (const float4*)qf32;
        const float4* mv4 = (const float4*)mv;
        float4* o4 = (float4*)out;

        for (int jt = 0; jt < 64; ++jt){
            {
                size_t grow = (size_t)b*LQ + i0 + (jt >> 1);
                int c = (w - 6)*64 + lane;      // 0..127
                if ((jt & 1) == 0) o4[grow*384 + 128 + c] = q4[grow*128 + c];
                else               o4[grow*384 + 256 + c] = mv4[b*128 + c];
            }
            SBAR;                               // B1
            if (jt <= 61) stageA((jt+2)*KT);
            if (jt <= 62) stageT((jt+1)*KT);
            VMCNT0; SBAR;                       // B2
        }
    }
}

extern "C" void kernel_launch(void* const* d_in, const int* in_sizes, int n_in,
                              void* d_out, int out_size, void* d_ws, size_t ws_size,
                              hipStream_t stream){
    const float* q     = (const float*)d_in[0];
    const float* v     = (const float*)d_in[1];
    const float* vmask = (const float*)d_in[2];
    const float* kern  = (const float*)d_in[3];
    float* out = (float*)d_out;
    char* ws = (char*)d_ws;

    const size_t SZ_QW = (size_t)NB*LQ*DOUT*2;       // 16 MB (layout kept)
    unsigned short* vbf = (unsigned short*)(ws + SZ_QW);
    unsigned short* vT  = (unsigned short*)(ws + 2*SZ_QW);
    unsigned short* kT  = (unsigned short*)(ws + 3*SZ_QW);
    float* mv   = (float*)(ws + 3*SZ_QW + 524288);                    // 16 KB
    float* part = (float*)(ws + 3*SZ_QW + 524288 + 16384);            // 1 MB
    // FIX: biasb AFTER part's full 1MB (was +131072 -> overlapped part -> NaN)
    unsigned short* biasb = (unsigned short*)(ws + 3*SZ_QW + 524288 + 16384 + 1048576);

    hipLaunchKernelGGL(prep_kT,  dim3(16,16),   dim3(256), 0, stream, kern, kT);
    hipLaunchKernelGGL(prep_v,   dim3(64,16,8), dim3(256), 0, stream, v, vmask, vbf, vT, part, biasb);
    hipLaunchKernelGGL(mv_final, dim3(8),       dim3(512), 0, stream, part, mv);
    hipLaunchKernelGGL(flash,    dim3(512),     dim3(512), 0, stream, kT, vbf, vT, biasb, q, mv, out);
}

// Round 17
// 168.316 us; speedup vs baseline: 1.3055x; 1.3055x over previous
//
#include <hip/hip_runtime.h>
#include <stdint.h>

// Problem: B=8, Lq=Lv=2048, Din=Dout=512, all f32 in/out.
// out[b][l][0:512)=o, [512:1024)=q, [1024:1536)=mv broadcast.
// v17 = r13 (best measured: 182.6us) + q/mv copy moved from the serial
// S-epilogue into the PV-wave loop (1 float4 store/lane/jt, hidden under
// PV's barrier slack). Everything else byte-identical to r13.

typedef __attribute__((ext_vector_type(8))) short short8v;
typedef __attribute__((ext_vector_type(4))) float f32x4;

#define LQ 2048
#define LV 2048
#define DIN 512
#define DOUT 512
#define NB 8
#define KT 32   // KV tile

__device__ __forceinline__ unsigned short f2bf(float x){
    union { float f; unsigned u; } v; v.f = x;
    unsigned r = v.u + 0x7fffu + ((v.u >> 16) & 1u);
    return (unsigned short)(r >> 16);
}

__device__ __forceinline__ void gload16(const void* g, void* l){
    __builtin_amdgcn_global_load_lds((const __attribute__((address_space(1))) void*)g,
                                     (__attribute__((address_space(3))) void*)l, 16, 0, 0);
}

#define SBAR   do{ __builtin_amdgcn_s_barrier(); __builtin_amdgcn_sched_barrier(0); }while(0)
#define LGKM0  do{ asm volatile("s_waitcnt lgkmcnt(0)" ::: "memory"); \
                   __builtin_amdgcn_sched_barrier(0); }while(0)
#define VMCNT4 do{ asm volatile("s_waitcnt vmcnt(4)" ::: "memory"); \
                   __builtin_amdgcn_sched_barrier(0); }while(0)
#define VMCNT0 do{ asm volatile("s_waitcnt vmcnt(0)" ::: "memory"); \
                   __builtin_amdgcn_sched_barrier(0); }while(0)

#define MFMA16(a, bfr, c) __builtin_amdgcn_mfma_f32_16x16x32_bf16(a, bfr, c, 0, 0, 0)

// kernel [DIN][DOUT] f32 -> kT [DOUT][DIN] bf16, scaled by 0.1 (folds the /10)
__global__ void prep_kT(const float* __restrict__ k, unsigned short* __restrict__ kT){
    __shared__ float tile[32][33];
    int tx = threadIdx.x & 31, ty = threadIdx.x >> 5;
    int kb = blockIdx.x, eb = blockIdx.y;
    #pragma unroll
    for (int p = 0; p < 4; ++p){
        int r = ty + p*8;
        tile[r][tx] = k[(size_t)(kb*32 + r)*DOUT + eb*32 + tx];
    }
    __syncthreads();
    #pragma unroll
    for (int p = 0; p < 4; ++p){
        int r = ty + p*8;
        kT[(size_t)(eb*32 + r)*DIN + kb*32 + tx] = f2bf(tile[tx][r] * 0.1f);
    }
}

// v f32 -> v bf16 (natural [b][j][e]) and vT bf16 ([b][e][j]) + masked-max partials
__global__ void prep_v(const float* __restrict__ v, const float* __restrict__ mask,
                       unsigned short* __restrict__ vbf, unsigned short* __restrict__ vT,
                       float* __restrict__ part){
    __shared__ float tile[32][33];
    __shared__ float pmax_l[8][33];
    int tx = threadIdx.x & 31, ty = threadIdx.x >> 5;
    int jb = blockIdx.x, eb = blockIdx.y, b = blockIdx.z;
    const size_t vbase = (size_t)b*LV*DOUT;
    #pragma unroll
    for (int p = 0; p < 4; ++p){
        int r = ty + p*8;
        size_t idx = vbase + (size_t)(jb*32 + r)*DOUT + eb*32 + tx;
        float val = v[idx];
        tile[r][tx] = val;
        vbf[idx] = f2bf(val);
    }
    __syncthreads();
    const size_t tbase = (size_t)b*DOUT*LV;
    #pragma unroll
    for (int p = 0; p < 4; ++p){
        int r = ty + p*8;
        vT[tbase + (size_t)(eb*32 + r)*LV + jb*32 + tx] = f2bf(tile[tx][r]);
    }
    float m = -3e38f;
    #pragma unroll
    for (int k2 = 0; k2 < 4; ++k2){
        int j = ty*4 + k2;
        float msk = mask[b*LV + jb*32 + j];
        m = fmaxf(m, tile[j][tx] - (1.0f - msk)*1e10f);
    }
    pmax_l[ty][tx] = m;
    __syncthreads();
    if (ty == 0){
        float mm = pmax_l[0][tx];
        #pragma unroll
        for (int c = 1; c < 8; ++c) mm = fmaxf(mm, pmax_l[c][tx]);
        part[((size_t)b*64 + jb)*DOUT + eb*32 + tx] = mm;
    }
}

__global__ void mv_final(const float* __restrict__ part, float* __restrict__ mv){
    int b = blockIdx.x; int e = threadIdx.x;
    float m = -3e38f;
    #pragma unroll
    for (int c = 0; c < 64; ++c) m = fmaxf(m, part[((size_t)b*64 + c)*DOUT + e]);
    mv[b*DOUT + e] = m;
}

__global__ __launch_bounds__(512, 1) void flash(const unsigned short* __restrict__ kT,
                                                const unsigned short* __restrict__ vbf,
                                                const unsigned short* __restrict__ vT,
                                                const float* __restrict__ mask,
                                                const float* __restrict__ qf32,
                                                const float* __restrict__ mv,
                                                float* __restrict__ out){
    __shared__ __align__(16) short A_t[2][KT*512];     // main: [j][e] unit^(j&7); prologue: qwL scratch
    __shared__ __align__(16) short T_t[2][512*KT];     // main: [e][j] slot^((e>>1)&3); prologue: kT chunks
    __shared__ __align__(16) float maskL[2048];        // 8KB mask row
    __shared__ short P_lds[2][4][16][40];              // parity x S-wave x row x j
    __shared__ float sB[64];

    const int bid = blockIdx.x;
    const int b = bid & 7, qt = bid >> 3;   // batch -> XCD pin
    const int tid = threadIdx.x;
    const int w = tid >> 6, lane = tid & 63;
    const int li = lane & 15, lg = lane >> 4;
    const int i0 = qt*64;

    const unsigned short* vb  = vbf + (size_t)b*LV*DOUT;
    const unsigned short* vTb = vT  + (size_t)b*DOUT*LV;
    const float* mkb = mask + b*LV;

    // staging lambdas (wave w covers rows/chunks w*4..+3)
    auto stageA = [&](int j0g, int buf){
        #pragma unroll
        for (int p = 0; p < 4; ++p){
            int j = w*4 + p;
            gload16(vb + (size_t)(j0g + j)*DOUT + ((lane ^ (j&7))*8), &A_t[buf][j*512]);
        }
    };
    auto stageT = [&](int j0g, int buf){
        #pragma unroll
        for (int p = 0; p < 4; ++p){
            int c = w*4 + p;
            int e = c*16 + (lane >> 2);
            gload16(vTb + (size_t)e*LV + j0g + (((lane&3) ^ ((lane>>3)&3))*8),
                    &T_t[buf][c*512]);
        }
    };
    // kT chunk staging (prologue): chunk ch = kT e-rows [ch*32, ch*32+32),
    // row er staged at chunkbuf + er*1KB with unit swizzle u^(er&7) (as stageA)
    auto stageK = [&](int ch, int buf){
        const unsigned short* kbase = kT + (size_t)ch*32*DIN;
        #pragma unroll
        for (int p = 0; p < 4; ++p){
            int er = w*4 + p;
            gload16(kbase + (size_t)er*DIN + ((lane ^ (er&7))*8),
                    (char*)&T_t[0][0] + buf*32768 + er*1024);
        }
    };

    // ======= common prologue: fused qw GEMM, kT staged via LDS chunks =======
    // S-wave w computes qw[i][e] for rows i = i0+w*16+li; result round-trips
    // through wave-local qwL (A_t region) to form the S-stage B-fragments.
    short8v qf[16];
    {
        short8v qb[16];
        if (w < 4){
            const float* qp = qf32 + (size_t)(b*LQ + i0 + w*16 + li)*DIN;
            #pragma unroll
            for (int ks = 0; ks < 16; ++ks){
                float4 lo = *(const float4*)(qp + ks*32 + lg*8);
                float4 hi = *(const float4*)(qp + ks*32 + lg*8 + 4);
                short8v t;
                t[0]=(short)f2bf(lo.x); t[1]=(short)f2bf(lo.y); t[2]=(short)f2bf(lo.z); t[3]=(short)f2bf(lo.w);
                t[4]=(short)f2bf(hi.x); t[5]=(short)f2bf(hi.y); t[6]=(short)f2bf(hi.z); t[7]=(short)f2bf(hi.w);
                qb[ks] = t;
            }
        }
        char* qwL = (char*)&A_t[0][0] + (w & 3)*16384;   // [16 rows][512 e] bf16, swizzled
        const int keyq = li & 7;

        stageK(0, 0); VMCNT0; SBAR;
        for (int ch = 0; ch < 16; ++ch){
            if (ch + 1 < 16) stageK(ch + 1, (ch + 1) & 1);
            if (w < 4){
                const short* Kc = (const short*)((char*)&T_t[0][0] + (ch & 1)*32768);
                #pragma unroll
                for (int half = 0; half < 2; ++half){
                    const int et = ch*2 + half;
                    const int er = half*16 + li;          // er&7 == li&7
                    f32x4 a0 = (f32x4){0.f,0.f,0.f,0.f}, a1 = a0;
                    #pragma unroll
                    for (int ks = 0; ks < 16; ks += 2){
                        short8v f0 = *(const short8v*)&Kc[er*512 + (((ks*4 + lg) ^ keyq)*8)];
                        a0 = MFMA16(f0, qb[ks], a0);
                        short8v f1 = *(const short8v*)&Kc[er*512 + ((((ks+1)*4 + lg) ^ keyq)*8)];
                        a1 = MFMA16(f1, qb[ks+1], a1);
                    }
                    unsigned p0 = (unsigned)f2bf(a0[0] + a1[0]) | ((unsigned)f2bf(a0[1] + a1[1]) << 16);
                    unsigned p1 = (unsigned)f2bf(a0[2] + a1[2]) | ((unsigned)f2bf(a0[3] + a1[3]) << 16);
                    unsigned long long pk = (unsigned long long)p0 | ((unsigned long long)p1 << 32);
                    *(unsigned long long*)(qwL + li*1024 + (((4*et + lg) ^ (keyq << 1))*8)) = pk;
                }
            }
            SBAR; VMCNT0; SBAR;    // reads of cur chunk done; next chunk landed
        }
        if (w < 4){
            #pragma unroll
            for (int ks = 0; ks < 16; ++ks)
                qf[ks] = *(const short8v*)(qwL + li*1024 + (((ks*4 + lg) ^ keyq)*16));
        }
        LGKM0; SBAR;               // P1: qwL reads retired; A_t/T_t free for staging
    }

    if (w < 4){
        // ===================== S role: 16 rows i0+w*16+li =====================
        stageA(0, 0); stageA(KT, 1); stageT(0, 0);
        gload16(mkb + w*256 + lane*4, (char*)maskL + w*1024);
        stageT(KT, 1);
        VMCNT4; SBAR;           // P2

        float srun = 0.0f;
        const int key = li & 7;

        auto computeS = [&](int jn){
            const int pn = jn & 1;
            const short* Ac = &A_t[pn][0];
            const int j0 = jn*KT;
            f32x4 mk0 = *(const f32x4*)&maskL[j0 + 4*lg];
            f32x4 mk1 = *(const f32x4*)&maskL[j0 + 16 + 4*lg];

            f32x4 s0a = (f32x4){0.f,0.f,0.f,0.f}, s0b = s0a, s1a = s0a, s1b = s0a;
            __builtin_amdgcn_s_setprio(1);
            #pragma unroll
            for (int ks = 0; ks < 8; ++ks){
                short8v a = *(const short8v*)&Ac[li*512 + (((ks*4 + lg)^key)*8)];
                s0a = MFMA16(a, qf[ks], s0a);
            }
            #pragma unroll
            for (int ks = 8; ks < 16; ++ks){
                short8v a = *(const short8v*)&Ac[li*512 + (((ks*4 + lg)^key)*8)];
                s0b = MFMA16(a, qf[ks], s0b);
            }
            #pragma unroll
            for (int ks = 0; ks < 8; ++ks){
                short8v a = *(const short8v*)&Ac[(li+16)*512 + (((ks*4 + lg)^key)*8)];
                s1a = MFMA16(a, qf[ks], s1a);
            }
            #pragma unroll
            for (int ks = 8; ks < 16; ++ks){
                short8v a = *(const short8v*)&Ac[(li+16)*512 + (((ks*4 + lg)^key)*8)];
                s1b = MFMA16(a, qf[ks], s1b);
            }
            __builtin_amdgcn_s_setprio(0);

            // max-free softmax: P = exp(S + bias) directly (|S| <= ~15; f32-safe)
            float p[8]; float psum = 0.f;
            #pragma unroll
            for (int r = 0; r < 4; ++r){
                p[r]     = __expf(s0a[r] + s0b[r] + (mk0[r] - 1.0f)*1e10f);
                p[4 + r] = __expf(s1a[r] + s1b[r] + (mk1[r] - 1.0f)*1e10f);
            }
            #pragma unroll
            for (int k = 0; k < 8; ++k) psum += p[k];
            srun += psum;   // per-lane partial; cross-lane reduce deferred to end

            #pragma unroll
            for (int s2 = 0; s2 < 2; ++s2)
                #pragma unroll
                for (int k = 0; k < 2; ++k){
                    unsigned lo2 = f2bf(p[s2*4 + 2*k]);
                    unsigned hi2 = f2bf(p[s2*4 + 2*k + 1]);
                    *(unsigned*)&P_lds[pn][w][li][s2*16 + 4*lg + 2*k] = lo2 | (hi2 << 16);
                }
        };

        computeS(0);
        LGKM0; SBAR;                        // B0b: P(0) published

        for (int jt = 0; jt < 64; ++jt){
            if (jt + 2 < 64) stageA((jt+2)*KT, jt & 1);   // A(jt) dead
            if (jt < 63) computeS(jt + 1);
            LGKM0; SBAR;                    // B1: P(jt+1) published; PV(jt) done
            if (jt + 2 < 64){ stageT((jt+2)*KT, jt & 1); VMCNT4; }
            else if (jt == 62){ VMCNT0; }
            SBAR;                           // B2
        }

        srun += __shfl_xor(srun, 16);
        srun += __shfl_xor(srun, 32);
        if (lg == 0) sB[w*16 + li] = srun;
        LGKM0; SBAR;                        // BE
        // (q/mv copy moved into the PV loop)
    } else {
        // ============ PV role: e-quarter [wp*128, +128), all 64 rows ============
        stageA(0, 0); stageA(KT, 1); stageT(0, 0);
        gload16(mkb + w*256 + lane*4, (char*)maskL + w*1024);
        stageT(KT, 1);
        VMCNT4; SBAR;                       // P2

        const int wp = w - 4;
        const int keyT = (li >> 1) & 3;
        const float4* q4  = (const float4*)qf32;
        const float4* mv4 = (const float4*)mv;
        float4* o4 = (float4*)out;
        const int cidx = wp*64 + lane;      // 0..255: 1 float4 of row jt per lane

        f32x4 acc[4][8];
        #pragma unroll
        for (int mt = 0; mt < 4; ++mt)
            #pragma unroll
            for (int nt = 0; nt < 8; ++nt) acc[mt][nt] = (f32x4){0.f,0.f,0.f,0.f};

        SBAR;                               // B0b

        for (int jt = 0; jt < 64; ++jt){
            const int pc = jt & 1;
            if (jt + 2 < 64) stageA((jt+2)*KT, jt & 1);

            short8v pa[4];
            #pragma unroll
            for (int mt = 0; mt < 4; ++mt)
                pa[mt] = *(const short8v*)&P_lds[pc][mt][li][lg*8];
            const short* Tc = &T_t[pc][0];
            __builtin_amdgcn_s_setprio(1);
            #pragma unroll
            for (int nt = 0; nt < 8; ++nt){
                int e_local = (wp*8 + nt)*16 + li;
                short8v vf = *(const short8v*)&Tc[e_local*KT + ((lg ^ keyT)*8)];
                #pragma unroll
                for (int mt = 0; mt < 4; ++mt)
                    acc[mt][nt] = MFMA16(pa[mt], vf, acc[mt][nt]);
            }
            __builtin_amdgcn_s_setprio(0);

            {   // in-loop q/mv copy: row jt of this block's 64 rows
                size_t grow = (size_t)b*LQ + i0 + jt;
                if (cidx < 128) o4[grow*384 + 128 + cidx] = q4[grow*128 + cidx];
                else            o4[grow*384 + 256 + (cidx - 128)] = mv4[b*128 + (cidx - 128)];
            }

            SBAR;                           // B1
            if (jt + 2 < 64){ stageT((jt+2)*KT, jt & 1); VMCNT4; }
            else if (jt == 62){ VMCNT0; }
            SBAR;                           // B2
        }

        SBAR;                               // BE: sB published

        #pragma unroll
        for (int mt = 0; mt < 4; ++mt){
            f32x4 s4 = *(const f32x4*)&sB[mt*16 + 4*lg];
            f32x4 inv;
            #pragma unroll
            for (int r = 0; r < 4; ++r) inv[r] = 1.0f / s4[r];
            #pragma unroll
            for (int nt = 0; nt < 8; ++nt)
                #pragma unroll
                for (int r = 0; r < 4; ++r)
                    out[(size_t)(b*LQ + i0 + mt*16 + 4*lg + r)*1536 + wp*128 + nt*16 + li]
                        = acc[mt][nt][r]*inv[r];
        }
    }
}

extern "C" void kernel_launch(void* const* d_in, const int* in_sizes, int n_in,
                              void* d_out, int out_size, void* d_ws, size_t ws_size,
                              hipStream_t stream){
    const float* q     = (const float*)d_in[0];
    const float* v     = (const float*)d_in[1];
    const float* vmask = (const float*)d_in[2];
    const float* kern  = (const float*)d_in[3];
    float* out = (float*)d_out;
    char* ws = (char*)d_ws;

    const size_t SZ_QW = (size_t)NB*LQ*DOUT*2;       // 16 MB (layout kept)
    unsigned short* vbf = (unsigned short*)(ws + SZ_QW);
    unsigned short* vT  = (unsigned short*)(ws + 2*SZ_QW);
    unsigned short* kT  = (unsigned short*)(ws + 3*SZ_QW);
    float* mv   = (float*)(ws + 3*SZ_QW + 524288);
    float* part = (float*)(ws + 3*SZ_QW + 524288 + 16384);

    hipLaunchKernelGGL(prep_kT,  dim3(16,16),   dim3(256), 0, stream, kern, kT);
    hipLaunchKernelGGL(prep_v,   dim3(64,16,8), dim3(256), 0, stream, v, vmask, vbf, vT, part);
    hipLaunchKernelGGL(mv_final, dim3(8),       dim3(512), 0, stream, part, mv);
    hipLaunchKernelGGL(flash,    dim3(256),     dim3(512), 0, stream, kT, vbf, vT, vmask, q, mv, out);
}